// Round 2
// baseline (151.972 us; speedup 1.0000x reference)
//
#include <hip/hip_runtime.h>
#include <hip/hip_bf16.h>
#include <math.h>

// Problem constants (AttentionSynapse): B=2, Tq=Tk=2048, E=Eq=Ek=1024, H=16, D=64
#define B_    2
#define TQ    2048
#define TK    2048
#define E_    1024
#define MTOT  4096   // B*TQ

typedef __attribute__((ext_vector_type(8))) short bf16x8;
typedef __attribute__((ext_vector_type(4))) float f32x4;

__device__ __forceinline__ unsigned short f2bf(float x) {
  unsigned int u = __float_as_uint(x);
  u += 0x7fff + ((u >> 16) & 1);      // round-to-nearest-even
  return (unsigned short)(u >> 16);
}

__device__ __forceinline__ void load_lds16(const void* g, void* l) {
  // async global->LDS, 16B/lane; LDS dest is wave-uniform base + lane*16
  __builtin_amdgcn_global_load_lds(
      (const __attribute__((address_space(1))) unsigned int*)g,
      (__attribute__((address_space(3))) unsigned int*)l, 16, 0, 0);
}

// ---------------------------------------------------------------------------
// prep: bf16-cast gq, gk, WK; scale WQ rows by Wmix[head] then cast.
// vec4 grid-stride over all four regions.
// ---------------------------------------------------------------------------
__global__ void prep_kernel(const float* __restrict__ gq, const float* __restrict__ gk,
                            const float* __restrict__ WQ, const float* __restrict__ WK,
                            const float* __restrict__ Wmix,
                            unsigned short* __restrict__ gqb, unsigned short* __restrict__ gkb,
                            unsigned short* __restrict__ wqb, unsigned short* __restrict__ wkb) {
  const int NGQ = (B_ * TQ * E_) / 4;   // 1048576 vec4
  const int NW  = (E_ * E_) / 4;        // 262144 vec4
  const int total = 2 * NGQ + 2 * NW;
  for (int idx = blockIdx.x * blockDim.x + threadIdx.x; idx < total;
       idx += gridDim.x * blockDim.x) {
    const float4* src; unsigned short* dst; int local; float scale = 1.0f;
    if (idx < NGQ)            { src = (const float4*)gq; dst = gqb; local = idx; }
    else if (idx < 2 * NGQ)   { src = (const float4*)gk; dst = gkb; local = idx - NGQ; }
    else if (idx < 2*NGQ+NW)  { src = (const float4*)WQ; dst = wqb; local = idx - 2*NGQ;
                                // row e = local/256; head = e/64 = local>>14
                                scale = Wmix[local >> 14]; }
    else                      { src = (const float4*)WK; dst = wkb; local = idx - 2*NGQ - NW; }
    float4 v = src[local];
    ushort4 o;
    o.x = f2bf(v.x * scale); o.y = f2bf(v.y * scale);
    o.z = f2bf(v.z * scale); o.w = f2bf(v.w * scale);
    ((ushort4*)dst)[local] = o;
  }
}

// ---------------------------------------------------------------------------
// Projection GEMM: C[m,n] = sum_k A[m,k]*W[n,k], bf16 in/out, fp32 accum.
// 128x128 tile, BK=32, 4 waves (2x2), 16x16x32 MFMA, global_load_lds staging.
// grid.z selects (gq,WQ')->qp vs (gk,WK)->kp.
// ---------------------------------------------------------------------------
__global__ __launch_bounds__(256) void proj_kernel(
    const unsigned short* __restrict__ gqb, const unsigned short* __restrict__ gkb,
    const unsigned short* __restrict__ wqb, const unsigned short* __restrict__ wkb,
    unsigned short* __restrict__ qp, unsigned short* __restrict__ kp) {
  const unsigned short* A = blockIdx.z ? gkb : gqb;
  const unsigned short* W = blockIdx.z ? wkb : wqb;
  unsigned short* C       = blockIdx.z ? kp  : qp;
  const int K = E_, N = E_;
  __shared__ unsigned short As[128 * 32];
  __shared__ unsigned short Bs[128 * 32];
  const int tid = threadIdx.x, wave = tid >> 6, lane = tid & 63;
  const int wrow = wave >> 1, wcol = wave & 1;
  const int m0 = blockIdx.y * 128, n0 = blockIdx.x * 128;
  f32x4 acc[4][4] = {};
  const int sr = wave * 32 + (lane >> 2);   // staged global row (per lane)
  const int sc = (lane & 3) * 8;            // staged col (bf16 elems)
  for (int k0 = 0; k0 < K; k0 += 32) {
    __syncthreads();
    load_lds16(A + (size_t)(m0 + sr) * K + k0 + sc,      As + (wave * 32) * 32);
    load_lds16(A + (size_t)(m0 + sr + 16) * K + k0 + sc, As + (wave * 32 + 16) * 32);
    load_lds16(W + (size_t)(n0 + sr) * K + k0 + sc,      Bs + (wave * 32) * 32);
    load_lds16(W + (size_t)(n0 + sr + 16) * K + k0 + sc, Bs + (wave * 32 + 16) * 32);
    __syncthreads();
    bf16x8 af[4], bw[4];
#pragma unroll
    for (int f = 0; f < 4; ++f) {
      af[f] = *(const bf16x8*)(As + (wrow * 64 + f * 16 + (lane & 15)) * 32 + (lane >> 4) * 8);
      bw[f] = *(const bf16x8*)(Bs + (wcol * 64 + f * 16 + (lane & 15)) * 32 + (lane >> 4) * 8);
    }
#pragma unroll
    for (int fi = 0; fi < 4; ++fi)
#pragma unroll
      for (int fj = 0; fj < 4; ++fj)
        acc[fi][fj] = __builtin_amdgcn_mfma_f32_16x16x32_bf16(af[fi], bw[fj], acc[fi][fj], 0, 0, 0);
  }
#pragma unroll
  for (int fi = 0; fi < 4; ++fi)
#pragma unroll
    for (int fj = 0; fj < 4; ++fj)
#pragma unroll
      for (int j = 0; j < 4; ++j) {
        int row = m0 + wrow * 64 + fi * 16 + (lane >> 4) * 4 + j;
        int col = n0 + wcol * 64 + fj * 16 + (lane & 15);
        C[(size_t)row * N + col] = f2bf(acc[fi][fj][j]);
      }
}

// ---------------------------------------------------------------------------
// Score GEMM + fused partial logsumexp.
// Per block: 128 q-rows x 128 k-cols, K=1024. After the K loop, per-row
// max and sum(exp(.-max)) over the 128 cols -> (m,s) partial per (row,ktile).
// ---------------------------------------------------------------------------
__global__ __launch_bounds__(256) void score_lse_kernel(
    const unsigned short* __restrict__ qp, const unsigned short* __restrict__ kp,
    float2* __restrict__ partials) {
  const int b = blockIdx.z;
  const unsigned short* A  = qp + (size_t)b * TQ * E_;
  const unsigned short* Bm = kp + (size_t)b * TK * E_;
  const int K = E_;
  __shared__ unsigned short As[128 * 32];
  __shared__ unsigned short Bs[128 * 32];
  __shared__ float redM[2][128];
  __shared__ float redS[2][128];
  const int tid = threadIdx.x, wave = tid >> 6, lane = tid & 63;
  const int wrow = wave >> 1, wcol = wave & 1;
  const int m0 = blockIdx.y * 128, n0 = blockIdx.x * 128;
  f32x4 acc[4][4] = {};
  const int sr = wave * 32 + (lane >> 2);
  const int sc = (lane & 3) * 8;
  for (int k0 = 0; k0 < K; k0 += 32) {
    __syncthreads();
    load_lds16(A  + (size_t)(m0 + sr) * K + k0 + sc,      As + (wave * 32) * 32);
    load_lds16(A  + (size_t)(m0 + sr + 16) * K + k0 + sc, As + (wave * 32 + 16) * 32);
    load_lds16(Bm + (size_t)(n0 + sr) * K + k0 + sc,      Bs + (wave * 32) * 32);
    load_lds16(Bm + (size_t)(n0 + sr + 16) * K + k0 + sc, Bs + (wave * 32 + 16) * 32);
    __syncthreads();
    bf16x8 af[4], bk[4];
#pragma unroll
    for (int f = 0; f < 4; ++f) {
      af[f] = *(const bf16x8*)(As + (wrow * 64 + f * 16 + (lane & 15)) * 32 + (lane >> 4) * 8);
      bk[f] = *(const bf16x8*)(Bs + (wcol * 64 + f * 16 + (lane & 15)) * 32 + (lane >> 4) * 8);
    }
#pragma unroll
    for (int fi = 0; fi < 4; ++fi)
#pragma unroll
      for (int fj = 0; fj < 4; ++fj)
        acc[fi][fj] = __builtin_amdgcn_mfma_f32_16x16x32_bf16(af[fi], bk[fj], acc[fi][fj], 0, 0, 0);
  }
  // ---- fused per-row LSE partial over this block's 128 cols ----
  const int grp = lane >> 4, li = lane & 15;
#pragma unroll
  for (int fi = 0; fi < 4; ++fi) {
#pragma unroll
    for (int j = 0; j < 4; ++j) {
      // row = wrow*64 + fi*16 + grp*4 + j ; this lane holds cols fj*16+li
      float m = fmaxf(fmaxf(acc[fi][0][j], acc[fi][1][j]),
                      fmaxf(acc[fi][2][j], acc[fi][3][j]));
#pragma unroll
      for (int msk = 1; msk < 16; msk <<= 1) m = fmaxf(m, __shfl_xor(m, msk, 64));
      float s = 0.f;
#pragma unroll
      for (int fj = 0; fj < 4; ++fj) s += expf(acc[fi][fj][j] - m);
#pragma unroll
      for (int msk = 1; msk < 16; msk <<= 1) s += __shfl_xor(s, msk, 64);
      if (li == 0) {
        int row = wrow * 64 + fi * 16 + grp * 4 + j;
        redM[wcol][row] = m;
        redS[wcol][row] = s;
      }
    }
  }
  __syncthreads();
  if (tid < 128) {
    float mA = redM[0][tid], mB = redM[1][tid];
    float M = fmaxf(mA, mB);
    float S = redS[0][tid] * expf(mA - M) + redS[1][tid] * expf(mB - M);
    int qrow = b * TQ + m0 + tid;
    partials[(size_t)qrow * 16 + blockIdx.x] = make_float2(M, S);
  }
}

// ---------------------------------------------------------------------------
// finalize: combine 16 (m,s) partials per q-row -> logsumexp
// ---------------------------------------------------------------------------
__global__ void finalize_kernel(const float2* __restrict__ partials, float* __restrict__ out) {
  int r = blockIdx.x * blockDim.x + threadIdx.x;
  if (r >= MTOT) return;
  const float2* p = partials + (size_t)r * 16;
  float M = p[0].x;
#pragma unroll
  for (int i = 1; i < 16; ++i) M = fmaxf(M, p[i].x);
  float S = 0.f;
#pragma unroll
  for (int i = 0; i < 16; ++i) S += p[i].y * expf(p[i].x - M);
  out[r] = logf(S) + M;
}

// ---------------------------------------------------------------------------
extern "C" void kernel_launch(void* const* d_in, const int* in_sizes, int n_in,
                              void* d_out, int out_size, void* d_ws, size_t ws_size,
                              hipStream_t stream) {
  const float* gq   = (const float*)d_in[0];
  const float* gk   = (const float*)d_in[1];
  const float* WQ   = (const float*)d_in[2];
  const float* WK   = (const float*)d_in[3];
  const float* Wmix = (const float*)d_in[4];
  float* out = (float*)d_out;

  char* ws = (char*)d_ws;
  unsigned short* gqb = (unsigned short*)(ws);                 // 8 MiB
  unsigned short* gkb = (unsigned short*)(ws + 8388608);       // 8 MiB
  unsigned short* wqb = (unsigned short*)(ws + 16777216);      // 2 MiB
  unsigned short* wkb = (unsigned short*)(ws + 18874368);      // 2 MiB
  unsigned short* qp  = (unsigned short*)(ws + 20971520);      // 8 MiB
  unsigned short* kp  = (unsigned short*)(ws + 29360128);      // 8 MiB
  float2* partials    = (float2*)(ws + 37748736);              // 512 KiB

  hipLaunchKernelGGL(prep_kernel, dim3(1024), dim3(256), 0, stream,
                     gq, gk, WQ, WK, Wmix, gqb, gkb, wqb, wkb);
  hipLaunchKernelGGL(proj_kernel, dim3(8, 32, 2), dim3(256), 0, stream,
                     gqb, gkb, wqb, wkb, qp, kp);
  hipLaunchKernelGGL(score_lse_kernel, dim3(16, 16, 2), dim3(256), 0, stream,
                     qp, kp, partials);
  hipLaunchKernelGGL(finalize_kernel, dim3(16), dim3(256), 0, stream,
                     partials, out);
}

// Round 3
// 150.694 us; speedup vs baseline: 1.0085x; 1.0085x over previous
//
#include <hip/hip_runtime.h>
#include <hip/hip_bf16.h>
#include <math.h>

// Problem constants (AttentionSynapse): B=2, Tq=Tk=2048, E=Eq=Ek=1024, H=16, D=64
#define B_    2
#define TQ    2048
#define TK    2048
#define E_    1024
#define MTOT  4096   // B*TQ

typedef __attribute__((ext_vector_type(8))) short bf16x8;
typedef __attribute__((ext_vector_type(4))) float f32x4;

__device__ __forceinline__ unsigned short f2bf(float x) {
  unsigned int u = __float_as_uint(x);
  u += 0x7fff + ((u >> 16) & 1);      // round-to-nearest-even
  return (unsigned short)(u >> 16);
}

__device__ __forceinline__ void load_lds16(const void* g, void* l) {
  // async global->LDS, 16B/lane; LDS dest is wave-uniform base + lane*16
  __builtin_amdgcn_global_load_lds(
      (const __attribute__((address_space(1))) unsigned int*)g,
      (__attribute__((address_space(3))) unsigned int*)l, 16, 0, 0);
}

// ---------------------------------------------------------------------------
// prep: bf16-cast gq, gk, WK; scale WQ rows by Wmix[head] then cast.
// ---------------------------------------------------------------------------
__global__ void prep_kernel(const float* __restrict__ gq, const float* __restrict__ gk,
                            const float* __restrict__ WQ, const float* __restrict__ WK,
                            const float* __restrict__ Wmix,
                            unsigned short* __restrict__ gqb, unsigned short* __restrict__ gkb,
                            unsigned short* __restrict__ wqb, unsigned short* __restrict__ wkb) {
  const int NGQ = (B_ * TQ * E_) / 4;   // 1048576 vec4
  const int NW  = (E_ * E_) / 4;        // 262144 vec4
  const int total = 2 * NGQ + 2 * NW;
  for (int idx = blockIdx.x * blockDim.x + threadIdx.x; idx < total;
       idx += gridDim.x * blockDim.x) {
    const float4* src; unsigned short* dst; int local; float scale = 1.0f;
    if (idx < NGQ)            { src = (const float4*)gq; dst = gqb; local = idx; }
    else if (idx < 2 * NGQ)   { src = (const float4*)gk; dst = gkb; local = idx - NGQ; }
    else if (idx < 2*NGQ+NW)  { src = (const float4*)WQ; dst = wqb; local = idx - 2*NGQ;
                                scale = Wmix[local >> 14]; }   // head = (4*local)/64/... = local>>14
    else                      { src = (const float4*)WK; dst = wkb; local = idx - 2*NGQ - NW; }
    float4 v = src[local];
    ushort4 o;
    o.x = f2bf(v.x * scale); o.y = f2bf(v.y * scale);
    o.z = f2bf(v.z * scale); o.w = f2bf(v.w * scale);
    ((ushort4*)dst)[local] = o;
  }
}

// ---------------------------------------------------------------------------
// Projection GEMM: C[m,n] = sum_k A[m,k]*W[n,k], bf16 in/out, fp32 accum.
// 128x128 tile, BK=32, 4 waves (2x2), DOUBLE-BUFFERED LDS, 2-phase schedule:
// ds_read(cur) -> stage(next into cur^1) -> MFMA -> barrier.
// ---------------------------------------------------------------------------
__global__ __launch_bounds__(256) void proj_kernel(
    const unsigned short* __restrict__ gqb, const unsigned short* __restrict__ gkb,
    const unsigned short* __restrict__ wqb, const unsigned short* __restrict__ wkb,
    unsigned short* __restrict__ qp, unsigned short* __restrict__ kp) {
  const unsigned short* A = blockIdx.z ? gkb : gqb;
  const unsigned short* W = blockIdx.z ? wkb : wqb;
  unsigned short* C       = blockIdx.z ? kp  : qp;
  const int K = E_, N = E_;
  __shared__ unsigned short As[2][128 * 32];
  __shared__ unsigned short Bs[2][128 * 32];
  const int tid = threadIdx.x, wave = tid >> 6, lane = tid & 63;
  const int wrow = wave >> 1, wcol = wave & 1;
  const int m0 = blockIdx.y * 128, n0 = blockIdx.x * 128;
  f32x4 acc[4][4] = {};
  const int sr = wave * 32 + (lane >> 2);   // staged global row (per lane)
  const int sc = (lane & 3) * 8;            // staged col (bf16 elems)
  const unsigned short* gA0 = A + (size_t)(m0 + sr) * K + sc;
  const unsigned short* gA1 = A + (size_t)(m0 + sr + 16) * K + sc;
  const unsigned short* gB0 = W + (size_t)(n0 + sr) * K + sc;
  const unsigned short* gB1 = W + (size_t)(n0 + sr + 16) * K + sc;

#define STAGE_P(b, k0)                                         \
  do {                                                         \
    load_lds16(gA0 + (k0), &As[b][(wave * 32) * 32]);          \
    load_lds16(gA1 + (k0), &As[b][(wave * 32 + 16) * 32]);     \
    load_lds16(gB0 + (k0), &Bs[b][(wave * 32) * 32]);          \
    load_lds16(gB1 + (k0), &Bs[b][(wave * 32 + 16) * 32]);     \
  } while (0)

  STAGE_P(0, 0);
  __syncthreads();                 // drains vmcnt -> buf0 ready
  const int NT = K / 32;           // 32 steps
  for (int t = 0; t < NT; ++t) {
    const int cur = t & 1;
    bf16x8 af[4], bw[4];
#pragma unroll
    for (int f = 0; f < 4; ++f) {
      af[f] = *(const bf16x8*)(&As[cur][(wrow * 64 + f * 16 + (lane & 15)) * 32 + (lane >> 4) * 8]);
      bw[f] = *(const bf16x8*)(&Bs[cur][(wcol * 64 + f * 16 + (lane & 15)) * 32 + (lane >> 4) * 8]);
    }
    if (t + 1 < NT) STAGE_P(cur ^ 1, (t + 1) * 32);   // prefetch overlaps MFMA below
#pragma unroll
    for (int fi = 0; fi < 4; ++fi)
#pragma unroll
      for (int fj = 0; fj < 4; ++fj)
        acc[fi][fj] = __builtin_amdgcn_mfma_f32_16x16x32_bf16(af[fi], bw[fj], acc[fi][fj], 0, 0, 0);
    __syncthreads();               // next buffer landed; cur free for rewrite
  }
#pragma unroll
  for (int fi = 0; fi < 4; ++fi)
#pragma unroll
    for (int fj = 0; fj < 4; ++fj)
#pragma unroll
      for (int j = 0; j < 4; ++j) {
        int row = m0 + wrow * 64 + fi * 16 + (lane >> 4) * 4 + j;
        int col = n0 + wcol * 64 + fj * 16 + (lane & 15);
        C[(size_t)row * N + col] = f2bf(acc[fi][fj][j]);
      }
#undef STAGE_P
}

// ---------------------------------------------------------------------------
// Score GEMM + fused partial logsumexp, same double-buffered 2-phase core.
// ---------------------------------------------------------------------------
__global__ __launch_bounds__(256) void score_lse_kernel(
    const unsigned short* __restrict__ qp, const unsigned short* __restrict__ kp,
    float2* __restrict__ partials) {
  const int b = blockIdx.z;
  const unsigned short* A  = qp + (size_t)b * TQ * E_;
  const unsigned short* Bm = kp + (size_t)b * TK * E_;
  const int K = E_;
  __shared__ unsigned short As[2][128 * 32];
  __shared__ unsigned short Bs[2][128 * 32];
  __shared__ float redM[2][128];
  __shared__ float redS[2][128];
  const int tid = threadIdx.x, wave = tid >> 6, lane = tid & 63;
  const int wrow = wave >> 1, wcol = wave & 1;
  const int m0 = blockIdx.y * 128, n0 = blockIdx.x * 128;
  f32x4 acc[4][4] = {};
  const int sr = wave * 32 + (lane >> 2);
  const int sc = (lane & 3) * 8;
  const unsigned short* gA0 = A  + (size_t)(m0 + sr) * K + sc;
  const unsigned short* gA1 = A  + (size_t)(m0 + sr + 16) * K + sc;
  const unsigned short* gB0 = Bm + (size_t)(n0 + sr) * K + sc;
  const unsigned short* gB1 = Bm + (size_t)(n0 + sr + 16) * K + sc;

#define STAGE_S(bf, k0)                                        \
  do {                                                         \
    load_lds16(gA0 + (k0), &As[bf][(wave * 32) * 32]);         \
    load_lds16(gA1 + (k0), &As[bf][(wave * 32 + 16) * 32]);    \
    load_lds16(gB0 + (k0), &Bs[bf][(wave * 32) * 32]);         \
    load_lds16(gB1 + (k0), &Bs[bf][(wave * 32 + 16) * 32]);    \
  } while (0)

  STAGE_S(0, 0);
  __syncthreads();
  const int NT = K / 32;
  for (int t = 0; t < NT; ++t) {
    const int cur = t & 1;
    bf16x8 af[4], bk[4];
#pragma unroll
    for (int f = 0; f < 4; ++f) {
      af[f] = *(const bf16x8*)(&As[cur][(wrow * 64 + f * 16 + (lane & 15)) * 32 + (lane >> 4) * 8]);
      bk[f] = *(const bf16x8*)(&Bs[cur][(wcol * 64 + f * 16 + (lane & 15)) * 32 + (lane >> 4) * 8]);
    }
    if (t + 1 < NT) STAGE_S(cur ^ 1, (t + 1) * 32);
#pragma unroll
    for (int fi = 0; fi < 4; ++fi)
#pragma unroll
      for (int fj = 0; fj < 4; ++fj)
        acc[fi][fj] = __builtin_amdgcn_mfma_f32_16x16x32_bf16(af[fi], bk[fj], acc[fi][fj], 0, 0, 0);
    __syncthreads();
  }
#undef STAGE_S
  // ---- fused per-row LSE partial over this block's 128 cols ----
  const int grp = lane >> 4, li = lane & 15;
#pragma unroll
  for (int fi = 0; fi < 4; ++fi) {
#pragma unroll
    for (int j = 0; j < 4; ++j) {
      // row = wrow*64 + fi*16 + grp*4 + j ; this lane holds cols fj*16+li
      float m = fmaxf(fmaxf(acc[fi][0][j], acc[fi][1][j]),
                      fmaxf(acc[fi][2][j], acc[fi][3][j]));
#pragma unroll
      for (int msk = 1; msk < 16; msk <<= 1) m = fmaxf(m, __shfl_xor(m, msk, 64));
      float s = 0.f;
#pragma unroll
      for (int fj = 0; fj < 4; ++fj) s += expf(acc[fi][fj][j] - m);
#pragma unroll
      for (int msk = 1; msk < 16; msk <<= 1) s += __shfl_xor(s, msk, 64);
      if (li == 0) {
        int row = wrow * 64 + fi * 16 + grp * 4 + j;
        redM[wcol][row] = m;
        redS[wcol][row] = s;
      }
    }
  }
  __syncthreads();
  if (tid < 128) {
    float mA = redM[0][tid], mB = redM[1][tid];
    float M = fmaxf(mA, mB);
    float S = redS[0][tid] * expf(mA - M) + redS[1][tid] * expf(mB - M);
    int qrow = b * TQ + m0 + tid;
    partials[(size_t)qrow * 16 + blockIdx.x] = make_float2(M, S);
  }
}

// ---------------------------------------------------------------------------
// finalize: combine 16 (m,s) partials per q-row -> logsumexp
// ---------------------------------------------------------------------------
__global__ void finalize_kernel(const float2* __restrict__ partials, float* __restrict__ out) {
  int r = blockIdx.x * blockDim.x + threadIdx.x;
  if (r >= MTOT) return;
  const float2* p = partials + (size_t)r * 16;
  float M = p[0].x;
#pragma unroll
  for (int i = 1; i < 16; ++i) M = fmaxf(M, p[i].x);
  float S = 0.f;
#pragma unroll
  for (int i = 0; i < 16; ++i) S += p[i].y * expf(p[i].x - M);
  out[r] = logf(S) + M;
}

// ---------------------------------------------------------------------------
extern "C" void kernel_launch(void* const* d_in, const int* in_sizes, int n_in,
                              void* d_out, int out_size, void* d_ws, size_t ws_size,
                              hipStream_t stream) {
  const float* gq   = (const float*)d_in[0];
  const float* gk   = (const float*)d_in[1];
  const float* WQ   = (const float*)d_in[2];
  const float* WK   = (const float*)d_in[3];
  const float* Wmix = (const float*)d_in[4];
  float* out = (float*)d_out;

  char* ws = (char*)d_ws;
  unsigned short* gqb = (unsigned short*)(ws);                 // 8 MiB
  unsigned short* gkb = (unsigned short*)(ws + 8388608);       // 8 MiB
  unsigned short* wqb = (unsigned short*)(ws + 16777216);      // 2 MiB
  unsigned short* wkb = (unsigned short*)(ws + 18874368);      // 2 MiB
  unsigned short* qp  = (unsigned short*)(ws + 20971520);      // 8 MiB
  unsigned short* kp  = (unsigned short*)(ws + 29360128);      // 8 MiB
  float2* partials    = (float2*)(ws + 37748736);              // 512 KiB

  hipLaunchKernelGGL(prep_kernel, dim3(1024), dim3(256), 0, stream,
                     gq, gk, WQ, WK, Wmix, gqb, gkb, wqb, wkb);
  hipLaunchKernelGGL(proj_kernel, dim3(8, 32, 2), dim3(256), 0, stream,
                     gqb, gkb, wqb, wkb, qp, kp);
  hipLaunchKernelGGL(score_lse_kernel, dim3(16, 16, 2), dim3(256), 0, stream,
                     qp, kp, partials);
  hipLaunchKernelGGL(finalize_kernel, dim3(16), dim3(256), 0, stream,
                     partials, out);
}